// Round 3
// baseline (288.472 us; speedup 1.0000x reference)
//
#include <hip/hip_runtime.h>
#include <math.h>

#define N_PER_TYPE 32000
#define NN (3 * N_PER_TYPE)          // 96000
#define EDGES (NN * 16)              // 1,536,000
#define NHEAD 4
#define DIM 8
#define HD 32
#define NEG 0.2f
#define NBLK ((NN + 255) / 256)      // 375 scan blocks

__global__ __launch_bounds__(256) void zero_kernel(int* __restrict__ deg,
                                                   int* __restrict__ ctr) {
    int i = blockIdx.x * 256 + threadIdx.x;
    if (i < NN) { deg[i] = 0; ctr[i] = 0; }
}

// Per-type linear embed + fused el/er computation.
// grid: 12000 blocks of 256 (8 nodes x 32 output lanes per block)
__global__ __launch_bounds__(256) void embed_kernel(
    const float* __restrict__ x0, const float* __restrict__ x1, const float* __restrict__ x2,
    const float* __restrict__ W0, const float* __restrict__ b0,
    const float* __restrict__ W1, const float* __restrict__ b1,
    const float* __restrict__ W2, const float* __restrict__ b2,
    const float* __restrict__ attn_l, const float* __restrict__ attn_r,
    float* __restrict__ h, float* __restrict__ el, float* __restrict__ er)
{
    __shared__ float Wlds[128 * 32];
    __shared__ float xl[8][128];

    int blk = blockIdx.x;
    int type = blk / 4000;
    int nb = blk % 4000;

    const float* x; const float* W; const float* b; int in_dim;
    if (type == 0)      { x = x0; W = W0; b = b0; in_dim = 128; }
    else if (type == 1) { x = x1; W = W1; b = b1; in_dim = 64; }
    else                { x = x2; W = W2; b = b2; in_dim = 32; }

    int tid = threadIdx.x;
    for (int i = tid; i < in_dim * 32; i += 256) Wlds[i] = W[i];
    int local0 = nb * 8;
    for (int i = tid; i < 8 * in_dim; i += 256) {
        int r = i / in_dim, c = i % in_dim;
        xl[r][c] = x[(local0 + r) * in_dim + c];
    }
    __syncthreads();

    int r = tid >> 5;      // node within block
    int j = tid & 31;      // output feature (head = j>>3, d = j&7)
    float acc = b[j];
    #pragma unroll 8
    for (int k = 0; k < in_dim; ++k)
        acc = fmaf(xl[r][k], Wlds[k * 32 + j], acc);

    int node = type * N_PER_TYPE + local0 + r;
    h[node * HD + j] = acc;

    float cl = acc * attn_l[j];
    float cr = acc * attn_r[j];
    #pragma unroll
    for (int off = 1; off < 8; off <<= 1) {
        cl += __shfl_xor(cl, off);
        cr += __shfl_xor(cr, off);
    }
    if ((j & 7) == 0) {
        int head = j >> 3;
        el[node * NHEAD + head] = cl;
        er[node * NHEAD + head] = cr;
    }
}

__global__ __launch_bounds__(256) void hist_kernel(const int* __restrict__ dst,
                                                   int* __restrict__ deg) {
    int t = blockIdx.x * 256 + threadIdx.x;
    if (t < EDGES) atomicAdd(&deg[dst[t]], 1);
}

// per-block exclusive scan of deg -> rs_local; block totals -> blocksum
__global__ __launch_bounds__(256) void scan1_kernel(const int* __restrict__ deg,
                                                    int* __restrict__ rs_local,
                                                    int* __restrict__ blocksum) {
    __shared__ int s[256];
    int tid = threadIdx.x;
    int i = blockIdx.x * 256 + tid;
    int v = (i < NN) ? deg[i] : 0;
    s[tid] = v;
    __syncthreads();
    #pragma unroll
    for (int off = 1; off < 256; off <<= 1) {
        int t = (tid >= off) ? s[tid - off] : 0;
        __syncthreads();
        s[tid] += t;
        __syncthreads();
    }
    if (i < NN) rs_local[i] = s[tid] - v;   // exclusive
    if (tid == 255) blocksum[blockIdx.x] = s[255];
}

// single-block exclusive scan of the 375 block sums
__global__ __launch_bounds__(512) void scan2_kernel(const int* __restrict__ blocksum,
                                                    int* __restrict__ blockoff) {
    __shared__ int s[512];
    int tid = threadIdx.x;
    int v = (tid < NBLK) ? blocksum[tid] : 0;
    s[tid] = v;
    __syncthreads();
    #pragma unroll
    for (int off = 1; off < 512; off <<= 1) {
        int t = (tid >= off) ? s[tid - off] : 0;
        __syncthreads();
        s[tid] += t;
        __syncthreads();
    }
    if (tid < NBLK) blockoff[tid] = s[tid] - v;
}

// scatter src ids into dst-grouped CSR order
__global__ __launch_bounds__(256) void scatter_kernel(
    const int* __restrict__ src, const int* __restrict__ dst,
    const int* __restrict__ rs_local, const int* __restrict__ blockoff,
    int* __restrict__ ctr, int* __restrict__ csr) {
    int t = blockIdx.x * 256 + threadIdx.x;
    if (t >= EDGES) return;
    int d = dst[t];
    int pos = atomicAdd(&ctr[d], 1);
    csr[rs_local[d] + blockoff[d >> 8] + pos] = src[t];
}

// one 32-lane group per dst node; register accumulation, no atomics.
// grid: NN*32/256 = 12000 blocks exact.
__global__ __launch_bounds__(256) void agg_kernel(
    const int* __restrict__ csr, const int* __restrict__ rs_local,
    const int* __restrict__ blockoff, const int* __restrict__ deg,
    const float* __restrict__ el, const float* __restrict__ er,
    const float* __restrict__ h, float* __restrict__ out)
{
    int t = blockIdx.x * 256 + threadIdx.x;
    int node = t >> 5;
    int j = t & 31;
    int head = j >> 3;
    int start = rs_local[node] + blockoff[node >> 8];
    int len = deg[node];
    float erd = er[node * NHEAD + head];
    float acc = 0.0f, den = 0.0f;

    int sv = (len > 0) ? csr[start] : 0;
    for (int i = 0; i < len; ++i) {
        int svn = (i + 1 < len) ? csr[start + i + 1] : 0;   // prefetch next index
        float x = el[sv * NHEAD + head] + erd;
        x = x > 0.0f ? x : NEG * x;
        float ex = __expf(x);
        den += ex;
        acc = fmaf(ex, h[sv * HD + j], acc);
        sv = svn;
    }
    float v = acc / (den + 1e-9f);
    out[node * HD + j] = v > 0.0f ? v : expm1f(v);
}

extern "C" void kernel_launch(void* const* d_in, const int* in_sizes, int n_in,
                              void* d_out, int out_size, void* d_ws, size_t ws_size,
                              hipStream_t stream) {
    const float* x0 = (const float*)d_in[0];
    const float* x1 = (const float*)d_in[1];
    const float* x2 = (const float*)d_in[2];
    const float* W0 = (const float*)d_in[3];
    const float* b0 = (const float*)d_in[4];
    const float* W1 = (const float*)d_in[5];
    const float* b1 = (const float*)d_in[6];
    const float* W2 = (const float*)d_in[7];
    const float* b2 = (const float*)d_in[8];
    const float* attn_l = (const float*)d_in[9];
    const float* attn_r = (const float*)d_in[10];
    // d_in[11] = type_mask, d_in[12..14] = idx0..idx2 (unused: contiguous layout)
    const int* src = (const int*)d_in[15];
    const int* dst = (const int*)d_in[16];
    float* out = (float*)d_out;

    // workspace layout:
    // h[NN*32] f | el[NN*4] f | er[NN*4] f | deg[NN] i | ctr[NN] i |
    // rs_local[NN] i | blockoff[512] i | blocksum[512] i | csr[EDGES] i   (~23 MB)
    float* h    = (float*)d_ws;
    float* el   = h + NN * HD;
    float* er   = el + NN * NHEAD;
    int* deg      = (int*)(er + NN * NHEAD);
    int* ctr      = deg + NN;
    int* rs_local = ctr + NN;
    int* blockoff = rs_local + NN;
    int* blocksum = blockoff + 512;
    int* csr      = blocksum + 512;

    embed_kernel<<<12000, 256, 0, stream>>>(x0, x1, x2, W0, b0, W1, b1, W2, b2,
                                            attn_l, attn_r, h, el, er);
    zero_kernel<<<(NN + 255) / 256, 256, 0, stream>>>(deg, ctr);
    hist_kernel<<<(EDGES + 255) / 256, 256, 0, stream>>>(dst, deg);
    scan1_kernel<<<NBLK, 256, 0, stream>>>(deg, rs_local, blocksum);
    scan2_kernel<<<1, 512, 0, stream>>>(blocksum, blockoff);
    scatter_kernel<<<(EDGES + 255) / 256, 256, 0, stream>>>(src, dst, rs_local, blockoff, ctr, csr);
    agg_kernel<<<NN * 32 / 256, 256, 0, stream>>>(csr, rs_local, blockoff, deg, el, er, h, out);
}

// Round 4
// 186.585 us; speedup vs baseline: 1.5461x; 1.5461x over previous
//
#include <hip/hip_runtime.h>
#include <hip/hip_bf16.h>
#include <math.h>

#define N_PER_TYPE 32000
#define NN (3 * N_PER_TYPE)          // 96000
#define EDGES (NN * 16)              // 1,536,000
#define NHEAD 4
#define HD 32
#define NEG 0.2f
#define NBLK ((NN + 255) / 256)      // 375 scan blocks

// Per-type linear embed + fused el/er computation. Also zeroes deg[] (12000*8 = NN).
// grid: 12000 blocks of 256 (8 nodes x 32 output lanes per block)
__global__ __launch_bounds__(256) void embed_kernel(
    const float* __restrict__ x0, const float* __restrict__ x1, const float* __restrict__ x2,
    const float* __restrict__ W0, const float* __restrict__ b0,
    const float* __restrict__ W1, const float* __restrict__ b1,
    const float* __restrict__ W2, const float* __restrict__ b2,
    const float* __restrict__ attn_l, const float* __restrict__ attn_r,
    __hip_bfloat16* __restrict__ h16, float* __restrict__ el, float* __restrict__ er,
    int* __restrict__ deg)
{
    __shared__ float Wlds[128 * 32];
    __shared__ float xl[8][128];

    int blk = blockIdx.x;
    int tid = threadIdx.x;
    if (tid < 8) deg[blk * 8 + tid] = 0;

    int type = blk / 4000;
    int nb = blk % 4000;

    const float* x; const float* W; const float* b; int in_dim;
    if (type == 0)      { x = x0; W = W0; b = b0; in_dim = 128; }
    else if (type == 1) { x = x1; W = W1; b = b1; in_dim = 64; }
    else                { x = x2; W = W2; b = b2; in_dim = 32; }

    for (int i = tid; i < in_dim * 32; i += 256) Wlds[i] = W[i];
    int local0 = nb * 8;
    for (int i = tid; i < 8 * in_dim; i += 256) {
        int r = i / in_dim, c = i % in_dim;
        xl[r][c] = x[(local0 + r) * in_dim + c];
    }
    __syncthreads();

    int r = tid >> 5;      // node within block
    int j = tid & 31;      // output feature (head = j>>3, d = j&7)
    float acc = b[j];
    #pragma unroll 8
    for (int k = 0; k < in_dim; ++k)
        acc = fmaf(xl[r][k], Wlds[k * 32 + j], acc);

    int node = type * N_PER_TYPE + local0 + r;
    h16[node * HD + j] = __float2bfloat16(acc);

    float cl = acc * attn_l[j];
    float cr = acc * attn_r[j];
    #pragma unroll
    for (int off = 1; off < 8; off <<= 1) {
        cl += __shfl_xor(cl, off);
        cr += __shfl_xor(cr, off);
    }
    if ((j & 7) == 0) {
        int head = j >> 3;
        el[node * NHEAD + head] = cl;
        er[node * NHEAD + head] = cr;
    }
}

// histogram + per-edge rank (atomic return value IS the rank)
__global__ __launch_bounds__(256) void hist_kernel(const int* __restrict__ dst,
                                                   int* __restrict__ deg,
                                                   int* __restrict__ rank) {
    int t = blockIdx.x * 256 + threadIdx.x;
    if (t < EDGES) rank[t] = atomicAdd(&deg[dst[t]], 1);
}

// per-block exclusive scan of deg -> rs_local; block totals -> blocksum
__global__ __launch_bounds__(256) void scan1_kernel(const int* __restrict__ deg,
                                                    int* __restrict__ rs_local,
                                                    int* __restrict__ blocksum) {
    __shared__ int s[256];
    int tid = threadIdx.x;
    int i = blockIdx.x * 256 + tid;
    int v = (i < NN) ? deg[i] : 0;
    s[tid] = v;
    __syncthreads();
    #pragma unroll
    for (int off = 1; off < 256; off <<= 1) {
        int t = (tid >= off) ? s[tid - off] : 0;
        __syncthreads();
        s[tid] += t;
        __syncthreads();
    }
    if (i < NN) rs_local[i] = s[tid] - v;   // exclusive
    if (tid == 255) blocksum[blockIdx.x] = s[255];
}

// single-block exclusive scan of the 375 block sums
__global__ __launch_bounds__(512) void scan2_kernel(const int* __restrict__ blocksum,
                                                    int* __restrict__ blockoff) {
    __shared__ int s[512];
    int tid = threadIdx.x;
    int v = (tid < NBLK) ? blocksum[tid] : 0;
    s[tid] = v;
    __syncthreads();
    #pragma unroll
    for (int off = 1; off < 512; off <<= 1) {
        int t = (tid >= off) ? s[tid - off] : 0;
        __syncthreads();
        s[tid] += t;
        __syncthreads();
    }
    if (tid < NBLK) blockoff[tid] = s[tid] - v;
}

// start[i] = rs_local[i] + blockoff[i>>8]  (single random-lookup array for scatter/agg)
__global__ __launch_bounds__(256) void scan3_kernel(const int* __restrict__ rs_local,
                                                    const int* __restrict__ blockoff,
                                                    int* __restrict__ start) {
    int i = blockIdx.x * 256 + threadIdx.x;
    if (i < NN) start[i] = rs_local[i] + blockoff[i >> 8];
}

// atomic-free scatter: rank precomputed, fire-and-forget random write
__global__ __launch_bounds__(256) void scatter_kernel(
    const int* __restrict__ src, const int* __restrict__ dst,
    const int* __restrict__ rank, const int* __restrict__ start,
    int* __restrict__ csr) {
    int t = blockIdx.x * 256 + threadIdx.x;
    if (t >= EDGES) return;
    int d = dst[t];
    csr[start[d] + rank[t]] = src[t];
}

// one 32-lane group per dst node; register accumulation, no atomics.
// Segment indices loaded 32-wide coalesced, broadcast via shuffle.
// grid: NN*32/256 = 12000 blocks exact.
__global__ __launch_bounds__(256) void agg_kernel(
    const int* __restrict__ csr, const int* __restrict__ start,
    const int* __restrict__ deg,
    const float* __restrict__ el, const float* __restrict__ er,
    const __hip_bfloat16* __restrict__ h16, float* __restrict__ out)
{
    int t = blockIdx.x * 256 + threadIdx.x;
    int node = t >> 5;
    int j = t & 31;
    int head = j >> 3;
    int s0 = start[node];
    int len = deg[node];
    float erd = er[node * NHEAD + head];
    float acc = 0.0f, den = 0.0f;

    for (int base = 0; base < len; base += 32) {
        int cnt = len - base; if (cnt > 32) cnt = 32;
        int svl = (j < cnt) ? csr[s0 + base + j] : 0;
        #pragma unroll 4
        for (int i = 0; i < cnt; ++i) {
            int sv = __shfl(svl, i, 32);
            float x = el[sv * NHEAD + head] + erd;
            x = x > 0.0f ? x : NEG * x;
            float ex = __expf(x);
            den += ex;
            acc = fmaf(ex, __bfloat162float(h16[sv * HD + j]), acc);
        }
    }
    float v = acc / (den + 1e-9f);
    out[node * HD + j] = v > 0.0f ? v : expm1f(v);
}

extern "C" void kernel_launch(void* const* d_in, const int* in_sizes, int n_in,
                              void* d_out, int out_size, void* d_ws, size_t ws_size,
                              hipStream_t stream) {
    const float* x0 = (const float*)d_in[0];
    const float* x1 = (const float*)d_in[1];
    const float* x2 = (const float*)d_in[2];
    const float* W0 = (const float*)d_in[3];
    const float* b0 = (const float*)d_in[4];
    const float* W1 = (const float*)d_in[5];
    const float* b1 = (const float*)d_in[6];
    const float* W2 = (const float*)d_in[7];
    const float* b2 = (const float*)d_in[8];
    const float* attn_l = (const float*)d_in[9];
    const float* attn_r = (const float*)d_in[10];
    // d_in[11] = type_mask, d_in[12..14] = idx0..idx2 (unused: contiguous layout)
    const int* src = (const int*)d_in[15];
    const int* dst = (const int*)d_in[16];
    float* out = (float*)d_out;

    // workspace layout:
    // h16[NN*32] bf16 | el[NN*4] f | er[NN*4] f | deg[NN] i | rank[EDGES] i |
    // rs_local[NN] i | blockoff[512] i | blocksum[512] i | start[NN] i | csr[EDGES] i  (~22 MB)
    __hip_bfloat16* h16 = (__hip_bfloat16*)d_ws;
    float* el = (float*)(h16 + NN * HD);
    float* er = el + NN * NHEAD;
    int* deg      = (int*)(er + NN * NHEAD);
    int* rank     = deg + NN;
    int* rs_local = rank + EDGES;
    int* blockoff = rs_local + NN;
    int* blocksum = blockoff + 512;
    int* start    = blocksum + 512;
    int* csr      = start + NN;

    embed_kernel<<<12000, 256, 0, stream>>>(x0, x1, x2, W0, b0, W1, b1, W2, b2,
                                            attn_l, attn_r, h16, el, er, deg);
    hist_kernel<<<(EDGES + 255) / 256, 256, 0, stream>>>(dst, deg, rank);
    scan1_kernel<<<NBLK, 256, 0, stream>>>(deg, rs_local, blocksum);
    scan2_kernel<<<1, 512, 0, stream>>>(blocksum, blockoff);
    scan3_kernel<<<(NN + 255) / 256, 256, 0, stream>>>(rs_local, blockoff, start);
    scatter_kernel<<<(EDGES + 255) / 256, 256, 0, stream>>>(src, dst, rank, start, csr);
    agg_kernel<<<NN * 32 / 256, 256, 0, stream>>>(csr, start, deg, el, er, h16, out);
}

// Round 5
// 156.798 us; speedup vs baseline: 1.8398x; 1.1900x over previous
//
#include <hip/hip_runtime.h>
#include <hip/hip_bf16.h>
#include <math.h>

#define N_PER_TYPE 32000
#define NN (3 * N_PER_TYPE)          // 96000
#define EDGES (NN * 16)              // 1,536,000
#define NHEAD 4
#define HD 32
#define NEG 0.2f
#define NBLK ((NN + 255) / 256)      // 375 scan blocks

__device__ __forceinline__ unsigned packbf(float a, float b) {
    __hip_bfloat162 t = __float22bfloat162_rn(make_float2(a, b));
    return *reinterpret_cast<unsigned*>(&t);
}

// Per-type linear embed + fused el/er computation. Also zeroes deg[].
// W staged in LDS as packed bf16 (halves LDS read BW); x staged f32.
// grid: 12000 blocks of 256 (8 nodes x 32 output lanes per block)
__global__ __launch_bounds__(256) void embed_kernel(
    const float* __restrict__ x0, const float* __restrict__ x1, const float* __restrict__ x2,
    const float* __restrict__ W0, const float* __restrict__ b0,
    const float* __restrict__ W1, const float* __restrict__ b1,
    const float* __restrict__ W2, const float* __restrict__ b2,
    const float* __restrict__ attn_l, const float* __restrict__ attn_r,
    __hip_bfloat16* __restrict__ h16, float* __restrict__ el, float* __restrict__ er,
    int* __restrict__ deg)
{
    __shared__ unsigned Wp[32 * 66];   // j-major, stride L2+2 (2-way bank alias = free)
    __shared__ float xl[8][128];

    int blk = blockIdx.x;
    int tid = threadIdx.x;
    if (tid < 8) deg[blk * 8 + tid] = 0;

    int type = blk / 4000;
    int nb = blk % 4000;

    const float* x; const float* W; const float* b; int in_dim, sh;
    if (type == 0)      { x = x0; W = W0; b = b0; in_dim = 128; sh = 7; }
    else if (type == 1) { x = x1; W = W1; b = b1; in_dim = 64;  sh = 6; }
    else                { x = x2; W = W2; b = b2; in_dim = 32;  sh = 5; }

    int L2 = in_dim >> 1;
    int STRIDE = L2 + 2;

    // stage W packed bf16: Wp[j*STRIDE + kk] = (W[2kk][j], W[2kk+1][j])
    for (int i = tid; i < 32 * L2; i += 256) {
        int j = i & 31, kk = i >> 5;
        float w0 = W[(2 * kk) * 32 + j];
        float w1 = W[(2 * kk + 1) * 32 + j];
        Wp[j * STRIDE + kk] = packbf(w0, w1);
    }
    int local0 = nb * 8;
    for (int i = tid; i < 8 * in_dim; i += 256) {
        int r = i >> sh, c = i & (in_dim - 1);
        xl[r][c] = x[(local0 + r) * in_dim + c];
    }
    __syncthreads();

    int r = tid >> 5;      // node within block
    int j = tid & 31;      // output feature (head = j>>3)
    float acc = b[j];
    const unsigned* wrow = &Wp[j * STRIDE];
    const float* xrow = xl[r];
    #pragma unroll 4
    for (int kk = 0; kk < L2; kk += 2) {        // 4 k per iteration
        unsigned p0 = wrow[kk], p1 = wrow[kk + 1];        // -> ds_read_b64
        float xa = xrow[2 * kk],     xb = xrow[2 * kk + 1];
        float xc = xrow[2 * kk + 2], xd = xrow[2 * kk + 3]; // -> ds_read_b128
        acc = fmaf(xa, __uint_as_float(p0 << 16),          acc);
        acc = fmaf(xb, __uint_as_float(p0 & 0xffff0000u),  acc);
        acc = fmaf(xc, __uint_as_float(p1 << 16),          acc);
        acc = fmaf(xd, __uint_as_float(p1 & 0xffff0000u),  acc);
    }

    int node = type * N_PER_TYPE + local0 + r;
    h16[node * HD + j] = __float2bfloat16(acc);

    float cl = acc * attn_l[j];
    float cr = acc * attn_r[j];
    #pragma unroll
    for (int off = 1; off < 8; off <<= 1) {
        cl += __shfl_xor(cl, off);
        cr += __shfl_xor(cr, off);
    }
    if ((j & 7) == 0) {
        int head = j >> 3;
        el[node * NHEAD + head] = cl;
        er[node * NHEAD + head] = cr;
    }
}

// histogram + per-edge rank (atomic return value IS the rank)
__global__ __launch_bounds__(256) void hist_kernel(const int* __restrict__ dst,
                                                   int* __restrict__ deg,
                                                   int* __restrict__ rank) {
    int t = blockIdx.x * 256 + threadIdx.x;
    if (t < EDGES) rank[t] = atomicAdd(&deg[dst[t]], 1);
}

// per-block exclusive scan of deg -> rs_local; block totals -> blocksum
__global__ __launch_bounds__(256) void scan1_kernel(const int* __restrict__ deg,
                                                    int* __restrict__ rs_local,
                                                    int* __restrict__ blocksum) {
    __shared__ int s[256];
    int tid = threadIdx.x;
    int i = blockIdx.x * 256 + tid;
    int v = (i < NN) ? deg[i] : 0;
    s[tid] = v;
    __syncthreads();
    #pragma unroll
    for (int off = 1; off < 256; off <<= 1) {
        int t = (tid >= off) ? s[tid - off] : 0;
        __syncthreads();
        s[tid] += t;
        __syncthreads();
    }
    if (i < NN) rs_local[i] = s[tid] - v;   // exclusive
    if (tid == 255) blocksum[blockIdx.x] = s[255];
}

// single-block exclusive scan of the 375 block sums
__global__ __launch_bounds__(512) void scan2_kernel(const int* __restrict__ blocksum,
                                                    int* __restrict__ blockoff) {
    __shared__ int s[512];
    int tid = threadIdx.x;
    int v = (tid < NBLK) ? blocksum[tid] : 0;
    s[tid] = v;
    __syncthreads();
    #pragma unroll
    for (int off = 1; off < 512; off <<= 1) {
        int t = (tid >= off) ? s[tid - off] : 0;
        __syncthreads();
        s[tid] += t;
        __syncthreads();
    }
    if (tid < NBLK) blockoff[tid] = s[tid] - v;
}

// start[i] = rs_local[i] + blockoff[i>>8]
__global__ __launch_bounds__(256) void scan3_kernel(const int* __restrict__ rs_local,
                                                    const int* __restrict__ blockoff,
                                                    int* __restrict__ start) {
    int i = blockIdx.x * 256 + threadIdx.x;
    if (i < NN) start[i] = rs_local[i] + blockoff[i >> 8];
}

// atomic-free scatter: rank precomputed, fire-and-forget random write
__global__ __launch_bounds__(256) void scatter_kernel(
    const int* __restrict__ src, const int* __restrict__ dst,
    const int* __restrict__ rank, const int* __restrict__ start,
    int* __restrict__ csr) {
    int t = blockIdx.x * 256 + threadIdx.x;
    if (t >= EDGES) return;
    int d = dst[t];
    csr[start[d] + rank[t]] = src[t];
}

// 16 lanes per dst node; lane owns feature pair (2j, 2j+1) loaded as packed bf16.
// Per 4-edge chunk, the 16 lanes compute the 16 (edge,head) scores exactly once
// and broadcast via shfl: 4x fewer expf / el-gathers, half the h-load instrs.
// grid: NN*16/256 = 6000 blocks exact.
__global__ __launch_bounds__(256) void agg_kernel(
    const int* __restrict__ csr, const int* __restrict__ start,
    const int* __restrict__ deg,
    const float* __restrict__ el, const float* __restrict__ er,
    const __hip_bfloat16* __restrict__ h16, float* __restrict__ out)
{
    int t = blockIdx.x * 256 + threadIdx.x;
    int node = t >> 4;
    int j = t & 15;            // feature-pair lane
    int head = j >> 2;         // aggregation head for features 2j,2j+1
    int hh = j & 3;            // score head this lane computes
    int s0 = start[node];
    int len = deg[node];
    float er_s = er[node * NHEAD + hh];
    float acc0 = 0.f, acc1 = 0.f, den = 0.f;
    const unsigned* hp = (const unsigned*)h16;   // packed bf16 pairs, 16 per node

    for (int base = 0; base < len; base += 16) {
        int cnt = len - base; if (cnt > 16) cnt = 16;
        int svl = (j < cnt) ? csr[s0 + base + j] : 0;
        for (int c = 0; c < cnt; c += 4) {
            // score for edge (c + j>>2), head (j&3)
            int se = c + (j >> 2);
            int sv_s = __shfl(svl, se, 16);
            float xs = el[sv_s * NHEAD + hh] + er_s;
            xs = fmaxf(xs, NEG * xs);                    // leaky_relu
            float exf = (se < cnt) ? __expf(xs) : 0.0f;  // 0 for padded edges
            #pragma unroll
            for (int i = 0; i < 4; ++i) {
                int sv = __shfl(svl, c + i, 16);
                float ex = __shfl(exf, (i << 2) + head, 16);
                unsigned p = hp[sv * 16 + j];
                den += ex;
                acc0 = fmaf(ex, __uint_as_float(p << 16),         acc0);
                acc1 = fmaf(ex, __uint_as_float(p & 0xffff0000u), acc1);
            }
        }
    }
    den += 1e-9f;
    float v0 = acc0 / den, v1 = acc1 / den;
    v0 = v0 > 0.f ? v0 : expm1f(v0);
    v1 = v1 > 0.f ? v1 : expm1f(v1);
    *reinterpret_cast<float2*>(out + node * HD + (j << 1)) = make_float2(v0, v1);
}

extern "C" void kernel_launch(void* const* d_in, const int* in_sizes, int n_in,
                              void* d_out, int out_size, void* d_ws, size_t ws_size,
                              hipStream_t stream) {
    const float* x0 = (const float*)d_in[0];
    const float* x1 = (const float*)d_in[1];
    const float* x2 = (const float*)d_in[2];
    const float* W0 = (const float*)d_in[3];
    const float* b0 = (const float*)d_in[4];
    const float* W1 = (const float*)d_in[5];
    const float* b1 = (const float*)d_in[6];
    const float* W2 = (const float*)d_in[7];
    const float* b2 = (const float*)d_in[8];
    const float* attn_l = (const float*)d_in[9];
    const float* attn_r = (const float*)d_in[10];
    // d_in[11] = type_mask, d_in[12..14] = idx0..idx2 (unused: contiguous layout)
    const int* src = (const int*)d_in[15];
    const int* dst = (const int*)d_in[16];
    float* out = (float*)d_out;

    // workspace layout (~22.4 MB, proven to fit):
    // h16[NN*32] bf16 | el[NN*4] f | er[NN*4] f | deg[NN] i | rank[EDGES] i |
    // rs_local[NN] i | blockoff[512] i | blocksum[512] i | start[NN] i | csr[EDGES] i
    __hip_bfloat16* h16 = (__hip_bfloat16*)d_ws;
    float* el = (float*)(h16 + NN * HD);
    float* er = el + NN * NHEAD;
    int* deg      = (int*)(er + NN * NHEAD);
    int* rank     = deg + NN;
    int* rs_local = rank + EDGES;
    int* blockoff = rs_local + NN;
    int* blocksum = blockoff + 512;
    int* start    = blocksum + 512;
    int* csr      = start + NN;

    embed_kernel<<<12000, 256, 0, stream>>>(x0, x1, x2, W0, b0, W1, b1, W2, b2,
                                            attn_l, attn_r, h16, el, er, deg);
    hist_kernel<<<(EDGES + 255) / 256, 256, 0, stream>>>(dst, deg, rank);
    scan1_kernel<<<NBLK, 256, 0, stream>>>(deg, rs_local, blocksum);
    scan2_kernel<<<1, 512, 0, stream>>>(blocksum, blockoff);
    scan3_kernel<<<(NN + 255) / 256, 256, 0, stream>>>(rs_local, blockoff, start);
    scatter_kernel<<<(EDGES + 255) / 256, 256, 0, stream>>>(src, dst, rank, start, csr);
    agg_kernel<<<NN * 16 / 256, 256, 0, stream>>>(csr, start, deg, el, er, h16, out);
}